// Round 1
// baseline (1162.001 us; speedup 1.0000x reference)
//
#include <hip/hip_runtime.h>
#include <hip/hip_bf16.h>
#include <cstdint>

typedef __attribute__((ext_vector_type(8))) short bf16x8;
typedef __attribute__((ext_vector_type(4))) float f32x4;

// ---------- helpers ----------
__device__ __forceinline__ float bf2f(unsigned short u) {
    return __uint_as_float(((unsigned)u) << 16);
}
__device__ __forceinline__ unsigned short f2bf(float x) {
    unsigned u = __float_as_uint(x);
    u += 0x7fffu + ((u >> 16) & 1u);   // round-to-nearest-even
    return (unsigned short)(u >> 16);
}
__device__ __forceinline__ float lrelu(float x) { return x >= 0.f ? x : 0.2f * x; }

// ---------- pack W [128,256] fp32 -> bf16 B-fragment layout ----------
// b-frag for (kk, n, quad): B[kk*32+quad*8+j][n], j=0..7 contiguous.
// packed elem index = ((kk*256 + n)*4 + quad)*8 + j
__global__ void packW(const float* __restrict__ W, unsigned short* __restrict__ Wp) {
    int idx = blockIdx.x * 256 + threadIdx.x;   // 32768 total
    int k = idx >> 8, n = idx & 255;
    int kk = k >> 5, r = k & 31, quad = r >> 3, j = r & 7;
    Wp[(((kk << 8) + n) * 4 + quad) * 8 + j] = f2bf(W[idx]);
}

// ---------- fold vectors: vv[k] = {W·attn_l h0, W·attn_l h1, W·attn_r h0, W·attn_r h1} ----------
// (x @ W) · attn  ==  x · (W @ attn)   -- lets the GEMM compute el/er from fp32 A directly.
__global__ void makeV(const float* __restrict__ W, const float* __restrict__ al,
                      const float* __restrict__ ar, float* __restrict__ vv) {
    int t = threadIdx.x;          // 256 threads: (k, head)
    int k = t >> 1, h = t & 1;
    const float* wp = W + k * 256 + h * 128;
    const float* alp = al + h * 128;
    const float* arp = ar + h * 128;
    float sl = 0.f, sr = 0.f;
#pragma unroll
    for (int d = 0; d < 128; d += 4) {
        float4 wv = *(const float4*)(wp + d);
        float4 av = *(const float4*)(alp + d);
        float4 rv = *(const float4*)(arp + d);
        sl += wv.x * av.x + wv.y * av.y + wv.z * av.z + wv.w * av.w;
        sr += wv.x * rv.x + wv.y * rv.y + wv.z * rv.z + wv.w * rv.w;
    }
    vv[k * 4 + h] = sl;
    vv[k * 4 + 2 + h] = sr;
}

// ---------- MFMA GEMM: [M,128]fp32 x [128,256] -> bf16 [M,256] + fused fold-vector dots ----------
// No A-LDS stage: per-lane direct global fragment loads + in-register cvt.
// Single barrier (C bounce). Wave w computes dots for its 16 rows via vv.
template<bool TAIL>
__device__ __forceinline__ void gemm_body(
    const float* __restrict__ A, const unsigned short* __restrict__ Wp,
    unsigned short* __restrict__ C, int M,
    const float4* __restrict__ vv,
    float* __restrict__ el, float* __restrict__ er,
    unsigned short* lds, int row0)
{
    const int t = threadIdx.x;
    const int w = t >> 6, lane = t & 63;
    const int quad = lane >> 4, l16 = lane & 15;
    const int col0w = w * 64;

    f32x4 acc[4][4];
#pragma unroll
    for (int rt = 0; rt < 4; rt++)
#pragma unroll
        for (int ct = 0; ct < 4; ct++) acc[rt][ct] = (f32x4)(0.f);

    float dl0 = 0.f, dl1 = 0.f, dr0 = 0.f, dr1 = 0.f;

#pragma unroll
    for (int kk = 0; kk < 4; kk++) {
        bf16x8 bfr[4];
#pragma unroll
        for (int ct = 0; ct < 4; ct++) {
            int n = col0w + ct * 16 + l16;
            bfr[ct] = *(const bf16x8*)(Wp + ((((kk << 8) + n) * 4 + quad) << 3));
        }
        float4 fa[4][2];
#pragma unroll
        for (int rt = 0; rt < 4; rt++) {
            int row = row0 + rt * 16 + l16;
            if (!TAIL || row < M) {
                const float* ap = A + (size_t)row * 128 + kk * 32 + quad * 8;
                fa[rt][0] = *(const float4*)ap;
                fa[rt][1] = *(const float4*)(ap + 4);
            } else {
                fa[rt][0] = make_float4(0.f, 0.f, 0.f, 0.f);
                fa[rt][1] = make_float4(0.f, 0.f, 0.f, 0.f);
            }
        }
#pragma unroll
        for (int rt = 0; rt < 4; rt++) {
            if (w == rt) {   // wave-uniform: wave w owns rows w*16..w*16+15 dots
                const float4* vp = vv + kk * 32 + quad * 8;
                float x0 = fa[rt][0].x, x1 = fa[rt][0].y, x2 = fa[rt][0].z, x3 = fa[rt][0].w;
                float x4 = fa[rt][1].x, x5 = fa[rt][1].y, x6 = fa[rt][1].z, x7 = fa[rt][1].w;
                float4 c0 = vp[0], c1 = vp[1], c2 = vp[2], c3 = vp[3];
                float4 c4 = vp[4], c5 = vp[5], c6 = vp[6], c7 = vp[7];
                dl0 += x0*c0.x + x1*c1.x + x2*c2.x + x3*c3.x + x4*c4.x + x5*c5.x + x6*c6.x + x7*c7.x;
                dl1 += x0*c0.y + x1*c1.y + x2*c2.y + x3*c3.y + x4*c4.y + x5*c5.y + x6*c6.y + x7*c7.y;
                dr0 += x0*c0.z + x1*c1.z + x2*c2.z + x3*c3.z + x4*c4.z + x5*c5.z + x6*c6.z + x7*c7.z;
                dr1 += x0*c0.w + x1*c1.w + x2*c2.w + x3*c3.w + x4*c4.w + x5*c5.w + x6*c6.w + x7*c7.w;
            }
            bf16x8 af;
            af[0] = (short)f2bf(fa[rt][0].x);
            af[1] = (short)f2bf(fa[rt][0].y);
            af[2] = (short)f2bf(fa[rt][0].z);
            af[3] = (short)f2bf(fa[rt][0].w);
            af[4] = (short)f2bf(fa[rt][1].x);
            af[5] = (short)f2bf(fa[rt][1].y);
            af[6] = (short)f2bf(fa[rt][1].z);
            af[7] = (short)f2bf(fa[rt][1].w);
#pragma unroll
            for (int ct = 0; ct < 4; ct++)
                acc[rt][ct] = __builtin_amdgcn_mfma_f32_16x16x32_bf16(af, bfr[ct], acc[rt][ct], 0, 0, 0);
        }
    }

    // ---- dot reduce across quads (lane bits 4,5) + store ----
    dl0 += __shfl_xor(dl0, 16); dl0 += __shfl_xor(dl0, 32);
    dl1 += __shfl_xor(dl1, 16); dl1 += __shfl_xor(dl1, 32);
    dr0 += __shfl_xor(dr0, 16); dr0 += __shfl_xor(dr0, 32);
    dr1 += __shfl_xor(dr1, 16); dr1 += __shfl_xor(dr1, 32);
    {
        int drow = row0 + w * 16 + l16;
        if (!TAIL || drow < M) {
            if (quad == 0) el[(size_t)drow * 2] = dl0;
            else if (quad == 1) el[(size_t)drow * 2 + 1] = dl1;
            else if (er) {
                if (quad == 2) er[(size_t)drow * 2] = dr0;
                else er[(size_t)drow * 2 + 1] = dr1;
            }
        }
    }

    // ---- bounce C to LDS [64][264] bf16 (C/D layout: col=lane&15, row=quad*4+reg) ----
#pragma unroll
    for (int rt = 0; rt < 4; rt++)
#pragma unroll
        for (int ct = 0; ct < 4; ct++)
#pragma unroll
            for (int r = 0; r < 4; r++)
                lds[(rt * 16 + quad * 4 + r) * 264 + col0w + ct * 16 + l16] = f2bf(acc[rt][ct][r]);
    __syncthreads();

    // ---- coalesced store ----
#pragma unroll
    for (int i = 0; i < 8; i++) {
        int flat = i * 4096 + t * 16;
        int row = flat >> 9;
        int cb = flat & 511;
        int grow = row0 + row;
        if (!TAIL || grow < M)
            *(uint4*)((char*)C + (size_t)grow * 512 + cb) =
                *(const uint4*)((const char*)lds + row * 528 + cb);
    }
}

__global__ __launch_bounds__(256, 4) void gemm_mfma(
    const float* __restrict__ A, const unsigned short* __restrict__ Wp,
    unsigned short* __restrict__ C, int M,
    const float4* __restrict__ vv,
    float* __restrict__ el, float* __restrict__ er)
{
    __shared__ unsigned short lds[16896];   // C-bounce 64x264 bf16
    int row0 = blockIdx.x * 64;
    if (row0 + 64 <= M) gemm_body<false>(A, Wp, C, M, vv, el, er, lds, row0);
    else                gemm_body<true >(A, Wp, C, M, vv, el, er, lds, row0);
}

// ---------- CSR build ----------
__global__ void hist_kernel(const int* __restrict__ dst, int* __restrict__ deg, int Nb) {
    int t = blockIdx.x * blockDim.x + threadIdx.x;
    if (t < Nb) atomicAdd(&deg[dst[t]], 1);
}

// 4096 elements per iteration: 4/thread sequential + wave scan + block scan
__global__ __launch_bounds__(1024) void scan4096(
    const int* __restrict__ deg, int* __restrict__ rowptr, int* __restrict__ wo, int n)
{
    __shared__ int wsum[16];
    int t = threadIdx.x, lane = t & 63, w = t >> 6;
    int carry = 0;
    for (int base = 0; base < n; base += 4096) {
        int i0 = base + t * 4;
        int4 v = make_int4(0, 0, 0, 0);
        if (i0 + 3 < n) v = *(const int4*)(deg + i0);
        else {
            if (i0 < n)     v.x = deg[i0];
            if (i0 + 1 < n) v.y = deg[i0 + 1];
            if (i0 + 2 < n) v.z = deg[i0 + 2];
            if (i0 + 3 < n) v.w = deg[i0 + 3];
        }
        int tsum = v.x + v.y + v.z + v.w;
        int x = tsum;
#pragma unroll
        for (int off = 1; off < 64; off <<= 1) {
            int y = __shfl_up(x, off);
            if (lane >= off) x += y;
        }
        if (lane == 63) wsum[w] = x;
        __syncthreads();
        if (w == 0) {
            int s = (lane < 16) ? wsum[lane] : 0;
#pragma unroll
            for (int off = 1; off < 16; off <<= 1) {
                int y = __shfl_up(s, off);
                if (lane >= off) s += y;
            }
            if (lane < 16) wsum[lane] = s;
        }
        __syncthreads();
        int wofs = (w > 0) ? wsum[w - 1] : 0;
        int total = wsum[15];
        int e0 = carry + wofs + (x - tsum);     // exclusive prefix of element i0
        int e1 = e0 + v.x, e2 = e1 + v.y, e3 = e2 + v.z;
        if (i0 < n)     { wo[i0]     = e0; rowptr[i0 + 1] = e1; }
        if (i0 + 1 < n) { wo[i0 + 1] = e1; rowptr[i0 + 2] = e2; }
        if (i0 + 2 < n) { wo[i0 + 2] = e2; rowptr[i0 + 3] = e3; }
        if (i0 + 3 < n) { wo[i0 + 3] = e3; rowptr[i0 + 4] = e3 + v.w; }
        __syncthreads();     // protect wsum before next iteration
        carry += total;
    }
    if (t == 0) rowptr[0] = 0;
}

// ---------- fill CSR + precompute per-edge attention logits ----------
__global__ void fill_kernel(const int* __restrict__ src, const int* __restrict__ dst,
                            const float* __restrict__ er, const float* __restrict__ elh,
                            const float* __restrict__ ele,
                            int* __restrict__ wo, int* __restrict__ sidx,
                            int* __restrict__ eidx, float4* __restrict__ logits, int Nb) {
    int t = blockIdx.x * blockDim.x + threadIdx.x;
    if (t >= Nb) return;
    int d = dst[t], s = src[t];
    int p = atomicAdd(&wo[d], 1);
    float e0 = er[(size_t)d * 2], e1 = er[(size_t)d * 2 + 1];
    float h0 = elh[(size_t)s * 2], h1 = elh[(size_t)s * 2 + 1];
    float l0 = ele[(size_t)t * 2], l1 = ele[(size_t)t * 2 + 1];
    sidx[p] = s;
    eidx[p] = t;
    logits[p] = make_float4(lrelu(h0 + e0), lrelu(h1 + e1), lrelu(l0 + e0), lrelu(l1 + e1));
}

// ---------- aggregation: wave per atom, wave-parallel logits + pipelined row gather ----------
__global__ __launch_bounds__(256) void aggregate(
    const unsigned short* __restrict__ h, const unsigned short* __restrict__ e,
    const unsigned short* __restrict__ u,
    const float* __restrict__ er, const float* __restrict__ elu,
    const int* __restrict__ rowptr, const int* __restrict__ sidx,
    const int* __restrict__ eidx, const float4* __restrict__ logits,
    const int* __restrict__ gid,
    float* __restrict__ hm, int Na)
{
    int wid = (int)((blockIdx.x * (unsigned)blockDim.x + threadIdx.x) >> 6);
    int lane = threadIdx.x & 63;
    if (wid >= Na) return;
    const int a = wid;
    const float er0 = er[(size_t)a * 2], er1 = er[(size_t)a * 2 + 1];
    const int g = gid[a];
    const float eul0 = lrelu(elu[(size_t)g * 2] + er0);
    const float eul1 = lrelu(elu[(size_t)g * 2 + 1] + er1);
    const int rb = rowptr[a], re = rowptr[a + 1];

    // ---- pass A: wave-parallel max over all edge logits ----
    float m0 = eul0, m1 = eul1;
    for (int base = rb; base < re; base += 64) {
        int i = base + lane;
        float lm0 = -1e30f, lm1 = -1e30f;
        if (i < re) {
            float4 lg = logits[i];
            lm0 = fmaxf(lg.x, lg.z);
            lm1 = fmaxf(lg.y, lg.w);
        }
#pragma unroll
        for (int off = 32; off >= 1; off >>= 1) {
            lm0 = fmaxf(lm0, __shfl_xor(lm0, off));
            lm1 = fmaxf(lm1, __shfl_xor(lm1, off));
        }
        m0 = fmaxf(m0, lm0);
        m1 = fmaxf(m1, lm1);
    }

    float es0 = __expf(eul0 - m0), es1 = __expf(eul1 - m1);
    const int head = lane >> 5;
    const int d4 = lane << 2;
    float acc0, acc1, acc2, acc3;
    {
        float eu_sel = head ? es1 : es0;
        ushort4 uv = *(const ushort4*)(u + (size_t)g * 256 + d4);
        acc0 = eu_sel * bf2f(uv.x); acc1 = eu_sel * bf2f(uv.y);
        acc2 = eu_sel * bf2f(uv.z); acc3 = eu_sel * bf2f(uv.w);
    }

    // ---- pass B: exp weights (parallel), then pipelined weighted row gather ----
    for (int base = rb; base < re; base += 64) {
        int n = min(64, re - base);
        float xh0 = 0.f, xh1 = 0.f, xe0 = 0.f, xe1 = 0.f;
        int sv = 0, bv = 0;
        if (lane < n) {
            float4 lg = logits[base + lane];
            xh0 = __expf(lg.x - m0); xh1 = __expf(lg.y - m1);
            xe0 = __expf(lg.z - m0); xe1 = __expf(lg.w - m1);
            sv = sidx[base + lane];
            bv = eidx[base + lane];
        }
        float s0 = xh0 + xe0, s1 = xh1 + xe1;
#pragma unroll
        for (int off = 32; off >= 1; off >>= 1) {
            s0 += __shfl_xor(s0, off);
            s1 += __shfl_xor(s1, off);
        }
        es0 += s0; es1 += s1;

        for (int j = 0; j < n; j++) {
            int s_j = __shfl(sv, j), b_j = __shfl(bv, j);
            float wh0 = __shfl(xh0, j), wh1 = __shfl(xh1, j);
            float we0 = __shfl(xe0, j), we1 = __shfl(xe1, j);
            float wh = head ? wh1 : wh0;
            float we = head ? we1 : we0;
            ushort4 hv = *(const ushort4*)(h + (size_t)s_j * 256 + d4);
            ushort4 ev = *(const ushort4*)(e + (size_t)b_j * 256 + d4);
            acc0 += wh * bf2f(hv.x) + we * bf2f(ev.x);
            acc1 += wh * bf2f(hv.y) + we * bf2f(ev.y);
            acc2 += wh * bf2f(hv.z) + we * bf2f(ev.z);
            acc3 += wh * bf2f(hv.w) + we * bf2f(ev.w);
        }
    }

    float inv = 1.f / (head ? es1 : es0);
    acc0 *= inv; acc1 *= inv; acc2 *= inv; acc3 *= inv;
    // mean over heads: lanes<32 combine with lane+32
    float p0 = __shfl(acc0, (lane + 32) & 63);
    float p1 = __shfl(acc1, (lane + 32) & 63);
    float p2 = __shfl(acc2, (lane + 32) & 63);
    float p3 = __shfl(acc3, (lane + 32) & 63);
    if (lane < 32) {
        float4 o = make_float4(0.5f * (acc0 + p0), 0.5f * (acc1 + p1),
                               0.5f * (acc2 + p2), 0.5f * (acc3 + p3));
        *(float4*)(hm + (size_t)a * 128 + d4) = o;
    }
}

// ---------- BatchNorm stats ----------
__global__ void bnstats(const float* __restrict__ hm, float* __restrict__ sums, int Na) {
    int t = threadIdx.x;
    int c = t & 127, half = t >> 7;
    float s = 0.f, ss = 0.f;
    for (int r = blockIdx.x * 2 + half; r < Na; r += gridDim.x * 2) {
        float v = hm[(size_t)r * 128 + c];
        s += v; ss += v * v;
    }
    atomicAdd(&sums[c], s);
    atomicAdd(&sums[128 + c], ss);
}

// ---------- BN normalize + ReLU ----------
__global__ void bnapply(const float* __restrict__ hm, const float* __restrict__ sums,
                        const float* __restrict__ gamma, const float* __restrict__ beta,
                        float* __restrict__ out, int Na) {
    int t = threadIdx.x;
    int c = t & 127, half = t >> 7;
    float invn = 1.f / (float)Na;
    float mean = sums[c] * invn;
    float var = sums[128 + c] * invn - mean * mean;
    float scale = gamma[c] * rsqrtf(var + 1e-5f);
    float shift = beta[c] - mean * scale;
    for (int r = blockIdx.x * 2 + half; r < Na; r += gridDim.x * 2) {
        float v = hm[(size_t)r * 128 + c] * scale + shift;
        out[(size_t)r * 128 + c] = fmaxf(v, 0.f);
    }
}

// ---------- launch ----------
extern "C" void kernel_launch(void* const* d_in, const int* in_sizes, int n_in,
                              void* d_out, int out_size, void* d_ws, size_t ws_size,
                              hipStream_t stream)
{
    const float* atom   = (const float*)d_in[0];
    const float* bondf  = (const float*)d_in[1];
    const float* globf  = (const float*)d_in[2];
    const float* Wa     = (const float*)d_in[3];
    const float* Wb     = (const float*)d_in[4];
    const float* Wg     = (const float*)d_in[5];
    const float* attn_l = (const float*)d_in[6];
    const float* attn_r = (const float*)d_in[7];
    const float* gamma  = (const float*)d_in[8];
    const float* beta   = (const float*)d_in[9];
    const int* src      = (const int*)d_in[10];
    const int* dst      = (const int*)d_in[11];
    const int* gid      = (const int*)d_in[12];
    const int Na = in_sizes[0] / 128;
    const int Nb = in_sizes[1] / 128;
    const int Ng = in_sizes[2] / 128;

    char* w = (char*)d_ws;
    size_t off = 0;
    auto alloc = [&](size_t bytes) -> void* {
        void* p = w + off;
        off = (off + bytes + 255) & ~(size_t)255;
        return p;
    };
    unsigned short* h   = (unsigned short*)alloc((size_t)Na * 256 * 2);
    unsigned short* e   = (unsigned short*)alloc((size_t)Nb * 256 * 2);
    unsigned short* u   = (unsigned short*)alloc((size_t)Ng * 256 * 2);
    unsigned short* Wpa = (unsigned short*)alloc(32768 * 2);
    unsigned short* Wpb = (unsigned short*)alloc(32768 * 2);
    unsigned short* Wpg = (unsigned short*)alloc(32768 * 2);
    float* vva  = (float*)alloc(512 * 4);
    float* vvb  = (float*)alloc(512 * 4);
    float* vvg  = (float*)alloc(512 * 4);
    float* er   = (float*)alloc((size_t)Na * 2 * 4);
    float* elh  = (float*)alloc((size_t)Na * 2 * 4);
    float* ele  = (float*)alloc((size_t)Nb * 2 * 4);
    float* elu  = (float*)alloc((size_t)Ng * 2 * 4);
    int* deg    = (int*)alloc((size_t)Na * 4);
    int* rowptr = (int*)alloc((size_t)(Na + 1) * 4);
    int* wo     = (int*)alloc((size_t)Na * 4);
    int* sidx   = (int*)alloc((size_t)Nb * 4);
    int* eidx   = (int*)alloc((size_t)Nb * 4);
    float4* logits = (float4*)alloc((size_t)Nb * 16);
    float* hm   = (float*)alloc((size_t)Na * 128 * 4);
    float* sums = (float*)alloc(256 * 4);

    hipMemsetAsync(deg, 0, (size_t)Na * 4, stream);
    hipMemsetAsync(sums, 0, 256 * 4, stream);

    packW<<<128, 256, 0, stream>>>(Wa, Wpa);
    packW<<<128, 256, 0, stream>>>(Wb, Wpb);
    packW<<<128, 256, 0, stream>>>(Wg, Wpg);
    makeV<<<1, 256, 0, stream>>>(Wa, attn_l, attn_r, vva);
    makeV<<<1, 256, 0, stream>>>(Wb, attn_l, attn_r, vvb);
    makeV<<<1, 256, 0, stream>>>(Wg, attn_l, attn_r, vvg);

    gemm_mfma<<<(Na + 63) / 64, 256, 0, stream>>>(atom, Wpa, h, Na, (const float4*)vva, elh, er);
    gemm_mfma<<<(Nb + 63) / 64, 256, 0, stream>>>(bondf, Wpb, e, Nb, (const float4*)vvb, ele, nullptr);
    gemm_mfma<<<(Ng + 63) / 64, 256, 0, stream>>>(globf, Wpg, u, Ng, (const float4*)vvg, elu, nullptr);

    hist_kernel<<<(Nb + 255) / 256, 256, 0, stream>>>(dst, deg, Nb);
    scan4096<<<1, 1024, 0, stream>>>(deg, rowptr, wo, Na);
    fill_kernel<<<(Nb + 255) / 256, 256, 0, stream>>>(src, dst, er, elh, ele,
                                                      wo, sidx, eidx, logits, Nb);

    aggregate<<<(Na + 3) / 4, 256, 0, stream>>>(h, e, u, er, elu,
                                                rowptr, sidx, eidx, logits, gid, hm, Na);
    bnstats<<<256, 256, 0, stream>>>(hm, sums, Na);
    bnapply<<<512, 256, 0, stream>>>(hm, sums, gamma, beta, (float*)d_out, Na);
}

// Round 3
// 864.937 us; speedup vs baseline: 1.3435x; 1.3435x over previous
//
#include <hip/hip_runtime.h>
#include <hip/hip_bf16.h>
#include <cstdint>

typedef __attribute__((ext_vector_type(8))) short bf16x8;
typedef __attribute__((ext_vector_type(4))) float f32x4;

// ---------- helpers ----------
__device__ __forceinline__ float bf2f(unsigned short u) {
    return __uint_as_float(((unsigned)u) << 16);
}
__device__ __forceinline__ unsigned short f2bf(float x) {
    unsigned u = __float_as_uint(x);
    u += 0x7fffu + ((u >> 16) & 1u);   // round-to-nearest-even
    return (unsigned short)(u >> 16);
}
__device__ __forceinline__ float lrelu(float x) { return x >= 0.f ? x : 0.2f * x; }

// ---------- pack all three W [128,256] fp32 -> bf16 B-fragment layout ----------
// b-frag for (kk, n, quad): B[kk*32+quad*8+j][n], j=0..7 contiguous.
// packed elem index = ((kk*256 + n)*4 + quad)*8 + j
__global__ void packW3(const float* __restrict__ Wa, const float* __restrict__ Wb,
                       const float* __restrict__ Wg,
                       unsigned short* __restrict__ Pa, unsigned short* __restrict__ Pb,
                       unsigned short* __restrict__ Pg) {
    int gidx = blockIdx.x * 256 + threadIdx.x;   // 3*32768 total
    int which = gidx >> 15, idx = gidx & 32767;
    const float* W = (which == 0) ? Wa : (which == 1) ? Wb : Wg;
    unsigned short* Wp = (which == 0) ? Pa : (which == 1) ? Pb : Pg;
    int k = idx >> 8, n = idx & 255;
    int kk = k >> 5, r = k & 31, quad = r >> 3, j = r & 7;
    Wp[(((kk << 8) + n) * 4 + quad) * 8 + j] = f2bf(W[idx]);
}

// ---------- fold vectors: vv4[k] = {W·attn_l h0, W·attn_l h1, W·attn_r h0, W·attn_r h1} ----------
// (x @ W) · attn  ==  x · (W @ attn)
__global__ void makeV3(const float* __restrict__ Wa, const float* __restrict__ Wb,
                       const float* __restrict__ Wg,
                       const float* __restrict__ al, const float* __restrict__ ar,
                       float* __restrict__ va, float* __restrict__ vb, float* __restrict__ vg) {
    const float* W = (blockIdx.x == 0) ? Wa : (blockIdx.x == 1) ? Wb : Wg;
    float* vv = (blockIdx.x == 0) ? va : (blockIdx.x == 1) ? vb : vg;
    int t = threadIdx.x;          // 256 threads: (k, head)
    int k = t >> 1, h = t & 1;
    const float* wp = W + k * 256 + h * 128;
    const float* alp = al + h * 128;
    const float* arp = ar + h * 128;
    float sl = 0.f, sr = 0.f;
#pragma unroll
    for (int d = 0; d < 128; d += 4) {
        float4 wv = *(const float4*)(wp + d);
        float4 av = *(const float4*)(alp + d);
        float4 rv = *(const float4*)(arp + d);
        sl += wv.x * av.x + wv.y * av.y + wv.z * av.z + wv.w * av.w;
        sr += wv.x * rv.x + wv.y * rv.y + wv.z * rv.z + wv.w * rv.w;
    }
    vv[k * 4 + h] = sl;
    vv[k * 4 + 2 + h] = sr;
}

// ---------- MFMA GEMM: [M,128]fp32 x [128,256] -> bf16 [M,256] + fused fold-vector dots ----------
// Zero LDS, zero barriers. Wave w owns rows w*16..w*16+15 (all 256 cols):
//   A loaded once per block (no inter-wave duplication), 8 upfront nontemporal loads/lane.
//   acc[16] f32x4 = 64 VGPR; B-frags transient from L1/L2-hot packed W.
template<bool TAIL>
__device__ __forceinline__ void gemm_body(
    const float* __restrict__ A, const unsigned short* __restrict__ Wp,
    unsigned short* __restrict__ C, int M, const float4* __restrict__ vv,
    float* __restrict__ el, float* __restrict__ er, int row0)
{
    const int t = threadIdx.x;
    const int w = t >> 6, lane = t & 63;
    const int quad = lane >> 4, l16 = lane & 15;
    const int arow = row0 + w * 16 + l16;
    const bool avalid = !TAIL || arow < M;
    const bool hasER = (er != nullptr);

    // ---- all A loads upfront (8 x f32x4 per lane, nontemporal) ----
    f32x4 fa0[4], fa1[4];
    const float* ap = A + (size_t)arow * 128 + quad * 8;
#pragma unroll
    for (int kk = 0; kk < 4; kk++) {
        if (avalid) {
            fa0[kk] = __builtin_nontemporal_load((const f32x4*)(ap + kk * 32));
            fa1[kk] = __builtin_nontemporal_load((const f32x4*)(ap + kk * 32 + 4));
        } else {
            fa0[kk] = (f32x4)(0.f);
            fa1[kk] = (f32x4)(0.f);
        }
    }

    // ---- fold-vector dots (fp32), before acc goes live ----
    float dl0 = 0.f, dl1 = 0.f, dr0 = 0.f, dr1 = 0.f;
#pragma unroll
    for (int kk = 0; kk < 4; kk++) {
        float x0 = fa0[kk].x, x1 = fa0[kk].y, x2 = fa0[kk].z, x3 = fa0[kk].w;
        float x4 = fa1[kk].x, x5 = fa1[kk].y, x6 = fa1[kk].z, x7 = fa1[kk].w;
        const float4* vp = vv + (kk << 5) + (quad << 3);
        {
            float4 c0 = vp[0], c1 = vp[1], c2 = vp[2], c3 = vp[3];
            dl0 += x0 * c0.x + x1 * c1.x + x2 * c2.x + x3 * c3.x;
            dl1 += x0 * c0.y + x1 * c1.y + x2 * c2.y + x3 * c3.y;
            if (hasER) {
                dr0 += x0 * c0.z + x1 * c1.z + x2 * c2.z + x3 * c3.z;
                dr1 += x0 * c0.w + x1 * c1.w + x2 * c2.w + x3 * c3.w;
            }
        }
        {
            float4 c4 = vp[4], c5 = vp[5], c6 = vp[6], c7 = vp[7];
            dl0 += x4 * c4.x + x5 * c5.x + x6 * c6.x + x7 * c7.x;
            dl1 += x4 * c4.y + x5 * c5.y + x6 * c6.y + x7 * c7.y;
            if (hasER) {
                dr0 += x4 * c4.z + x5 * c5.z + x6 * c6.z + x7 * c7.z;
                dr1 += x4 * c4.w + x5 * c5.w + x6 * c6.w + x7 * c7.w;
            }
        }
    }
    // reduce across quads (lane bits 4,5); store one value per quad
    dl0 += __shfl_xor(dl0, 16); dl0 += __shfl_xor(dl0, 32);
    dl1 += __shfl_xor(dl1, 16); dl1 += __shfl_xor(dl1, 32);
    if (hasER) {
        dr0 += __shfl_xor(dr0, 16); dr0 += __shfl_xor(dr0, 32);
        dr1 += __shfl_xor(dr1, 16); dr1 += __shfl_xor(dr1, 32);
    }
    if (avalid) {
        if (quad == 0) el[(size_t)arow * 2] = dl0;
        else if (quad == 1) el[(size_t)arow * 2 + 1] = dl1;
        else if (hasER) {
            if (quad == 2) er[(size_t)arow * 2] = dr0;
            else er[(size_t)arow * 2 + 1] = dr1;
        }
    }

    // ---- MFMA: 16 col-tiles, B-frags transient ----
    f32x4 acc[16];
#pragma unroll
    for (int ct = 0; ct < 16; ct++) acc[ct] = (f32x4)(0.f);

#pragma unroll
    for (int kk = 0; kk < 4; kk++) {
        bf16x8 af;
        af[0] = (short)f2bf(fa0[kk].x);
        af[1] = (short)f2bf(fa0[kk].y);
        af[2] = (short)f2bf(fa0[kk].z);
        af[3] = (short)f2bf(fa0[kk].w);
        af[4] = (short)f2bf(fa1[kk].x);
        af[5] = (short)f2bf(fa1[kk].y);
        af[6] = (short)f2bf(fa1[kk].z);
        af[7] = (short)f2bf(fa1[kk].w);
        const unsigned short* wpk = Wp + (((kk << 8) + l16) << 5) + (quad << 3);
#pragma unroll
        for (int ct = 0; ct < 16; ct++) {
            bf16x8 bfr = *(const bf16x8*)(wpk + (ct << 9));
            acc[ct] = __builtin_amdgcn_mfma_f32_16x16x32_bf16(af, bfr, acc[ct], 0, 0, 0);
        }
    }

    // ---- direct C store: lane holds (col=l16+ct*16, rows quad*4+r) of wave's stripe ----
    const int crow0 = row0 + w * 16 + quad * 4;
#pragma unroll
    for (int r = 0; r < 4; r++) {
        int crow = crow0 + r;
        if (!TAIL || crow < M) {
            unsigned short* cp = C + (size_t)crow * 256 + l16;
#pragma unroll
            for (int ct = 0; ct < 16; ct++)
                cp[ct * 16] = f2bf(acc[ct][r]);
        }
    }
}

__global__ __launch_bounds__(256, 4) void gemm_mfma(
    const float* __restrict__ A, const unsigned short* __restrict__ Wp,
    unsigned short* __restrict__ C, int M, const float4* __restrict__ vv,
    float* __restrict__ el, float* __restrict__ er)
{
    int row0 = blockIdx.x * 64;
    if (row0 + 64 <= M) gemm_body<false>(A, Wp, C, M, vv, el, er, row0);
    else                gemm_body<true >(A, Wp, C, M, vv, el, er, row0);
}

// ---------- CSR build ----------
__global__ void hist_kernel(const int* __restrict__ dst, int* __restrict__ deg, int Nb) {
    int t = blockIdx.x * blockDim.x + threadIdx.x;
    if (t < Nb) atomicAdd(&deg[dst[t]], 1);
}

// 4096 elements per iteration: 4/thread sequential + wave scan + block scan
__global__ __launch_bounds__(1024) void scan4096(
    const int* __restrict__ deg, int* __restrict__ rowptr, int* __restrict__ wo, int n)
{
    __shared__ int wsum[16];
    int t = threadIdx.x, lane = t & 63, w = t >> 6;
    int carry = 0;
    for (int base = 0; base < n; base += 4096) {
        int i0 = base + t * 4;
        int4 v = make_int4(0, 0, 0, 0);
        if (i0 + 3 < n) v = *(const int4*)(deg + i0);
        else {
            if (i0 < n)     v.x = deg[i0];
            if (i0 + 1 < n) v.y = deg[i0 + 1];
            if (i0 + 2 < n) v.z = deg[i0 + 2];
            if (i0 + 3 < n) v.w = deg[i0 + 3];
        }
        int tsum = v.x + v.y + v.z + v.w;
        int x = tsum;
#pragma unroll
        for (int off = 1; off < 64; off <<= 1) {
            int y = __shfl_up(x, off);
            if (lane >= off) x += y;
        }
        if (lane == 63) wsum[w] = x;
        __syncthreads();
        if (w == 0) {
            int s = (lane < 16) ? wsum[lane] : 0;
#pragma unroll
            for (int off = 1; off < 16; off <<= 1) {
                int y = __shfl_up(s, off);
                if (lane >= off) s += y;
            }
            if (lane < 16) wsum[lane] = s;
        }
        __syncthreads();
        int wofs = (w > 0) ? wsum[w - 1] : 0;
        int total = wsum[15];
        int e0 = carry + wofs + (x - tsum);     // exclusive prefix of element i0
        int e1 = e0 + v.x, e2 = e1 + v.y, e3 = e2 + v.z;
        if (i0 < n)     { wo[i0]     = e0; rowptr[i0 + 1] = e1; }
        if (i0 + 1 < n) { wo[i0 + 1] = e1; rowptr[i0 + 2] = e2; }
        if (i0 + 2 < n) { wo[i0 + 2] = e2; rowptr[i0 + 3] = e3; }
        if (i0 + 3 < n) { wo[i0 + 3] = e3; rowptr[i0 + 4] = e3 + v.w; }
        __syncthreads();     // protect wsum before next iteration
        carry += total;
    }
    if (t == 0) rowptr[0] = 0;
}

// ---------- fill CSR + precompute per-edge attention logits ----------
__global__ void fill_kernel(const int* __restrict__ src, const int* __restrict__ dst,
                            const float* __restrict__ er, const float* __restrict__ elh,
                            const float* __restrict__ ele,
                            int* __restrict__ wo, int* __restrict__ sidx,
                            int* __restrict__ eidx, float4* __restrict__ logits, int Nb) {
    int t = blockIdx.x * blockDim.x + threadIdx.x;
    if (t >= Nb) return;
    int d = dst[t], s = src[t];
    int p = atomicAdd(&wo[d], 1);
    float e0 = er[(size_t)d * 2], e1 = er[(size_t)d * 2 + 1];
    float h0 = elh[(size_t)s * 2], h1 = elh[(size_t)s * 2 + 1];
    float l0 = ele[(size_t)t * 2], l1 = ele[(size_t)t * 2 + 1];
    sidx[p] = s;
    eidx[p] = t;
    logits[p] = make_float4(lrelu(h0 + e0), lrelu(h1 + e1), lrelu(l0 + e0), lrelu(l1 + e1));
}

// ---------- aggregation: wave per atom, wave-parallel logits + pipelined row gather ----------
__global__ __launch_bounds__(256) void aggregate(
    const unsigned short* __restrict__ h, const unsigned short* __restrict__ e,
    const unsigned short* __restrict__ u,
    const float* __restrict__ er, const float* __restrict__ elu,
    const int* __restrict__ rowptr, const int* __restrict__ sidx,
    const int* __restrict__ eidx, const float4* __restrict__ logits,
    const int* __restrict__ gid,
    float* __restrict__ hm, int Na)
{
    int wid = (int)((blockIdx.x * (unsigned)blockDim.x + threadIdx.x) >> 6);
    int lane = threadIdx.x & 63;
    if (wid >= Na) return;
    const int a = wid;
    const float er0 = er[(size_t)a * 2], er1 = er[(size_t)a * 2 + 1];
    const int g = gid[a];
    const float eul0 = lrelu(elu[(size_t)g * 2] + er0);
    const float eul1 = lrelu(elu[(size_t)g * 2 + 1] + er1);
    const int rb = rowptr[a], re = rowptr[a + 1];

    // ---- pass A: wave-parallel max over all edge logits ----
    float m0 = eul0, m1 = eul1;
    for (int base = rb; base < re; base += 64) {
        int i = base + lane;
        float lm0 = -1e30f, lm1 = -1e30f;
        if (i < re) {
            float4 lg = logits[i];
            lm0 = fmaxf(lg.x, lg.z);
            lm1 = fmaxf(lg.y, lg.w);
        }
#pragma unroll
        for (int off = 32; off >= 1; off >>= 1) {
            lm0 = fmaxf(lm0, __shfl_xor(lm0, off));
            lm1 = fmaxf(lm1, __shfl_xor(lm1, off));
        }
        m0 = fmaxf(m0, lm0);
        m1 = fmaxf(m1, lm1);
    }

    float es0 = __expf(eul0 - m0), es1 = __expf(eul1 - m1);
    const int head = lane >> 5;
    const int d4 = lane << 2;
    float acc0, acc1, acc2, acc3;
    {
        float eu_sel = head ? es1 : es0;
        ushort4 uv = *(const ushort4*)(u + (size_t)g * 256 + d4);
        acc0 = eu_sel * bf2f(uv.x); acc1 = eu_sel * bf2f(uv.y);
        acc2 = eu_sel * bf2f(uv.z); acc3 = eu_sel * bf2f(uv.w);
    }

    // ---- pass B: exp weights (parallel), then pipelined weighted row gather ----
    for (int base = rb; base < re; base += 64) {
        int n = min(64, re - base);
        float xh0 = 0.f, xh1 = 0.f, xe0 = 0.f, xe1 = 0.f;
        int sv = 0, bv = 0;
        if (lane < n) {
            float4 lg = logits[base + lane];
            xh0 = __expf(lg.x - m0); xh1 = __expf(lg.y - m1);
            xe0 = __expf(lg.z - m0); xe1 = __expf(lg.w - m1);
            sv = sidx[base + lane];
            bv = eidx[base + lane];
        }
        float s0 = xh0 + xe0, s1 = xh1 + xe1;
#pragma unroll
        for (int off = 32; off >= 1; off >>= 1) {
            s0 += __shfl_xor(s0, off);
            s1 += __shfl_xor(s1, off);
        }
        es0 += s0; es1 += s1;

        for (int j = 0; j < n; j++) {
            int s_j = __shfl(sv, j), b_j = __shfl(bv, j);
            float wh0 = __shfl(xh0, j), wh1 = __shfl(xh1, j);
            float we0 = __shfl(xe0, j), we1 = __shfl(xe1, j);
            float wh = head ? wh1 : wh0;
            float we = head ? we1 : we0;
            ushort4 hv = *(const ushort4*)(h + (size_t)s_j * 256 + d4);
            ushort4 ev = *(const ushort4*)(e + (size_t)b_j * 256 + d4);
            acc0 += wh * bf2f(hv.x) + we * bf2f(ev.x);
            acc1 += wh * bf2f(hv.y) + we * bf2f(ev.y);
            acc2 += wh * bf2f(hv.z) + we * bf2f(ev.z);
            acc3 += wh * bf2f(hv.w) + we * bf2f(ev.w);
        }
    }

    float inv = 1.f / (head ? es1 : es0);
    acc0 *= inv; acc1 *= inv; acc2 *= inv; acc3 *= inv;
    // mean over heads: lanes<32 combine with lane+32
    float p0 = __shfl(acc0, (lane + 32) & 63);
    float p1 = __shfl(acc1, (lane + 32) & 63);
    float p2 = __shfl(acc2, (lane + 32) & 63);
    float p3 = __shfl(acc3, (lane + 32) & 63);
    if (lane < 32) {
        float4 o = make_float4(0.5f * (acc0 + p0), 0.5f * (acc1 + p1),
                               0.5f * (acc2 + p2), 0.5f * (acc3 + p3));
        *(float4*)(hm + (size_t)a * 128 + d4) = o;
    }
}

// ---------- BatchNorm stats ----------
__global__ void bnstats(const float* __restrict__ hm, float* __restrict__ sums, int Na) {
    int t = threadIdx.x;
    int c = t & 127, half = t >> 7;
    float s = 0.f, ss = 0.f;
    for (int r = blockIdx.x * 2 + half; r < Na; r += gridDim.x * 2) {
        float v = hm[(size_t)r * 128 + c];
        s += v; ss += v * v;
    }
    atomicAdd(&sums[c], s);
    atomicAdd(&sums[128 + c], ss);
}

// ---------- BN normalize + ReLU ----------
__global__ void bnapply(const float* __restrict__ hm, const float* __restrict__ sums,
                        const float* __restrict__ gamma, const float* __restrict__ beta,
                        float* __restrict__ out, int Na) {
    int t = threadIdx.x;
    int c = t & 127, half = t >> 7;
    float invn = 1.f / (float)Na;
    float mean = sums[c] * invn;
    float var = sums[128 + c] * invn - mean * mean;
    float scale = gamma[c] * rsqrtf(var + 1e-5f);
    float shift = beta[c] - mean * scale;
    for (int r = blockIdx.x * 2 + half; r < Na; r += gridDim.x * 2) {
        float v = hm[(size_t)r * 128 + c] * scale + shift;
        out[(size_t)r * 128 + c] = fmaxf(v, 0.f);
    }
}

// ---------- launch ----------
extern "C" void kernel_launch(void* const* d_in, const int* in_sizes, int n_in,
                              void* d_out, int out_size, void* d_ws, size_t ws_size,
                              hipStream_t stream)
{
    const float* atom   = (const float*)d_in[0];
    const float* bondf  = (const float*)d_in[1];
    const float* globf  = (const float*)d_in[2];
    const float* Wa     = (const float*)d_in[3];
    const float* Wb     = (const float*)d_in[4];
    const float* Wg     = (const float*)d_in[5];
    const float* attn_l = (const float*)d_in[6];
    const float* attn_r = (const float*)d_in[7];
    const float* gamma  = (const float*)d_in[8];
    const float* beta   = (const float*)d_in[9];
    const int* src      = (const int*)d_in[10];
    const int* dst      = (const int*)d_in[11];
    const int* gid      = (const int*)d_in[12];
    const int Na = in_sizes[0] / 128;
    const int Nb = in_sizes[1] / 128;
    const int Ng = in_sizes[2] / 128;

    char* w = (char*)d_ws;
    size_t off = 0;
    auto alloc = [&](size_t bytes) -> void* {
        void* p = w + off;
        off = (off + bytes + 255) & ~(size_t)255;
        return p;
    };
    unsigned short* h   = (unsigned short*)alloc((size_t)Na * 256 * 2);
    unsigned short* e   = (unsigned short*)alloc((size_t)Nb * 256 * 2);
    unsigned short* u   = (unsigned short*)alloc((size_t)Ng * 256 * 2);
    unsigned short* Wpa = (unsigned short*)alloc(32768 * 2);
    unsigned short* Wpb = (unsigned short*)alloc(32768 * 2);
    unsigned short* Wpg = (unsigned short*)alloc(32768 * 2);
    float* vva  = (float*)alloc(512 * 4);
    float* vvb  = (float*)alloc(512 * 4);
    float* vvg  = (float*)alloc(512 * 4);
    float* er   = (float*)alloc((size_t)Na * 2 * 4);
    float* elh  = (float*)alloc((size_t)Na * 2 * 4);
    float* ele  = (float*)alloc((size_t)Nb * 2 * 4);
    float* elu  = (float*)alloc((size_t)Ng * 2 * 4);
    int* deg    = (int*)alloc((size_t)Na * 4);
    int* rowptr = (int*)alloc((size_t)(Na + 1) * 4);
    int* wo     = (int*)alloc((size_t)Na * 4);
    int* sidx   = (int*)alloc((size_t)Nb * 4);
    int* eidx   = (int*)alloc((size_t)Nb * 4);
    float4* logits = (float4*)alloc((size_t)Nb * 16);
    float* hm   = (float*)alloc((size_t)Na * 128 * 4);
    float* sums = (float*)alloc(256 * 4);

    hipMemsetAsync(deg, 0, (size_t)Na * 4, stream);
    hipMemsetAsync(sums, 0, 256 * 4, stream);

    packW3<<<384, 256, 0, stream>>>(Wa, Wb, Wg, Wpa, Wpb, Wpg);
    makeV3<<<3, 256, 0, stream>>>(Wa, Wb, Wg, attn_l, attn_r, vva, vvb, vvg);

    gemm_mfma<<<(Na + 63) / 64, 256, 0, stream>>>(atom, Wpa, h, Na, (const float4*)vva, elh, er);
    gemm_mfma<<<(Nb + 63) / 64, 256, 0, stream>>>(bondf, Wpb, e, Nb, (const float4*)vvb, ele, nullptr);
    gemm_mfma<<<(Ng + 63) / 64, 256, 0, stream>>>(globf, Wpg, u, Ng, (const float4*)vvg, elu, nullptr);

    hist_kernel<<<(Nb + 255) / 256, 256, 0, stream>>>(dst, deg, Nb);
    scan4096<<<1, 1024, 0, stream>>>(deg, rowptr, wo, Na);
    fill_kernel<<<(Nb + 255) / 256, 256, 0, stream>>>(src, dst, er, elh, ele,
                                                      wo, sidx, eidx, logits, Nb);

    aggregate<<<(Na + 3) / 4, 256, 0, stream>>>(h, e, u, er, elu,
                                                rowptr, sidx, eidx, logits, gid, hm, Na);
    bnstats<<<256, 256, 0, stream>>>(hm, sums, Na);
    bnapply<<<512, 256, 0, stream>>>(hm, sums, gamma, beta, (float*)d_out, Na);
}

// Round 4
// 720.878 us; speedup vs baseline: 1.6119x; 1.1998x over previous
//
#include <hip/hip_runtime.h>
#include <hip/hip_bf16.h>
#include <cstdint>

typedef __attribute__((ext_vector_type(8))) short bf16x8;
typedef __attribute__((ext_vector_type(4))) float f32x4;

// ---------- helpers ----------
__device__ __forceinline__ float bf2f(unsigned short u) {
    return __uint_as_float(((unsigned)u) << 16);
}
__device__ __forceinline__ unsigned short f2bf(float x) {
    unsigned u = __float_as_uint(x);
    u += 0x7fffu + ((u >> 16) & 1u);   // round-to-nearest-even
    return (unsigned short)(u >> 16);
}
__device__ __forceinline__ float lrelu(float x) { return x >= 0.f ? x : 0.2f * x; }

// ---------- pack all three W [128,256] fp32 -> bf16 B-fragment layout ----------
// b-frag for (kk, n, quad): B[kk*32+quad*8+j][n], j=0..7 contiguous.
// packed elem index = ((kk*256 + n)*4 + quad)*8 + j
__global__ void packW3(const float* __restrict__ Wa, const float* __restrict__ Wb,
                       const float* __restrict__ Wg,
                       unsigned short* __restrict__ Pa, unsigned short* __restrict__ Pb,
                       unsigned short* __restrict__ Pg) {
    int gidx = blockIdx.x * 256 + threadIdx.x;   // 3*32768 total
    int which = gidx >> 15, idx = gidx & 32767;
    const float* W = (which == 0) ? Wa : (which == 1) ? Wb : Wg;
    unsigned short* Wp = (which == 0) ? Pa : (which == 1) ? Pb : Pg;
    int k = idx >> 8, n = idx & 255;
    int kk = k >> 5, r = k & 31, quad = r >> 3, j = r & 7;
    Wp[(((kk << 8) + n) * 4 + quad) * 8 + j] = f2bf(W[idx]);
}

// ---------- fold tile: V[k][fc] = {W.al h0, W.al h1, W.ar h0, W.ar h1, 0...}, packed
// as a 16-col bf16 B-fragment tile: Vp[((kk*16+fc)*4+q)*8+j] = V[kk*32+q*8+j][fc]
__global__ void makeVpack(const float* __restrict__ Wa, const float* __restrict__ Wb,
                          const float* __restrict__ Wg,
                          const float* __restrict__ al, const float* __restrict__ ar,
                          unsigned short* __restrict__ Va, unsigned short* __restrict__ Vb,
                          unsigned short* __restrict__ Vg) {
    const float* W = (blockIdx.x == 0) ? Wa : (blockIdx.x == 1) ? Wb : Wg;
    unsigned short* Vp = (blockIdx.x == 0) ? Va : (blockIdx.x == 1) ? Vb : Vg;
    __shared__ float sv[128][4];
    int t = threadIdx.x;          // 256 threads: (k, head)
    int k = t >> 1, hh = t & 1;
    const float* wp = W + k * 256 + hh * 128;
    const float* alp = al + hh * 128;
    const float* arp = ar + hh * 128;
    float sl = 0.f, sr = 0.f;
#pragma unroll
    for (int d = 0; d < 128; d += 4) {
        float4 wv = *(const float4*)(wp + d);
        float4 av = *(const float4*)(alp + d);
        float4 rv = *(const float4*)(arp + d);
        sl += wv.x * av.x + wv.y * av.y + wv.z * av.z + wv.w * av.w;
        sr += wv.x * rv.x + wv.y * rv.y + wv.z * rv.z + wv.w * rv.w;
    }
    sv[k][hh] = sl;
    sv[k][2 + hh] = sr;
    __syncthreads();
#pragma unroll
    for (int ii = 0; ii < 16; ii++) {
        int idx = t * 16 + ii;                 // 4096 packed elems
        int j = idx & 7, q = (idx >> 3) & 3, fc = (idx >> 5) & 15, kk = idx >> 9;
        int kg = kk * 32 + q * 8 + j;
        float val = (fc < 4) ? sv[kg][fc] : 0.f;
        Vp[idx] = f2bf(val);
    }
}

// ---------- fused MFMA GEMM over [atom|bond|glob]: [M,128]fp32 x [128,256] -> bf16 [M,256]
// + fold tile -> el (and er for atoms) straight out of the accumulator.
// Structure: staged A->LDS (coalesced), MFMA from LDS, C bounce->LDS, coalesced dwordx4 store.
template<bool TAIL>
__device__ __forceinline__ void gemm_body(
    const float* __restrict__ A, const unsigned short* __restrict__ Wp,
    const unsigned short* __restrict__ Vp,
    unsigned short* __restrict__ C, int M,
    float* __restrict__ el, float* __restrict__ er,
    unsigned short* lds, int row0)
{
    const int t = threadIdx.x;
    const int w = t >> 6, lane = t & 63;
    const int quad = lane >> 4, l16 = lane & 15;
    const int col0w = w * 64;

    // ---- stage A: 64 rows x 128 fp32 -> bf16 LDS [64][136] ----
#pragma unroll
    for (int i = 0; i < 8; i++) {
        int flat = i * 4096 + t * 16;           // byte offset in 64x512B fp32 tile
        int row = flat >> 9;
        int colf = (flat & 511) >> 2;
        float4 v = make_float4(0.f, 0.f, 0.f, 0.f);
        if (!TAIL || row0 + row < M) v = *(const float4*)(A + (size_t)(row0 + row) * 128 + colf);
        unsigned u0 = (unsigned)f2bf(v.x) | ((unsigned)f2bf(v.y) << 16);
        unsigned u1 = (unsigned)f2bf(v.z) | ((unsigned)f2bf(v.w) << 16);
        *(uint2*)(&lds[row * 136 + colf]) = make_uint2(u0, u1);
    }
    __syncthreads();

    f32x4 acc[4][4];
    f32x4 accf = (f32x4)(0.f);
#pragma unroll
    for (int rt = 0; rt < 4; rt++)
#pragma unroll
        for (int ct = 0; ct < 4; ct++) acc[rt][ct] = (f32x4)(0.f);

#pragma unroll
    for (int kk = 0; kk < 4; kk++) {
        bf16x8 af[4], bfr[4], afw, vfr;
#pragma unroll
        for (int rt = 0; rt < 4; rt++)
            af[rt] = *(const bf16x8*)(&lds[(rt * 16 + l16) * 136 + kk * 32 + quad * 8]);
        afw = *(const bf16x8*)(&lds[(w * 16 + l16) * 136 + kk * 32 + quad * 8]);
#pragma unroll
        for (int ct = 0; ct < 4; ct++) {
            int n = col0w + ct * 16 + l16;
            bfr[ct] = *(const bf16x8*)(Wp + ((((kk << 8) + n) * 4 + quad) << 3));
        }
        vfr = *(const bf16x8*)(Vp + ((((kk << 4) + l16) * 4 + quad) << 3));
#pragma unroll
        for (int rt = 0; rt < 4; rt++)
#pragma unroll
            for (int ct = 0; ct < 4; ct++)
                acc[rt][ct] = __builtin_amdgcn_mfma_f32_16x16x32_bf16(af[rt], bfr[ct], acc[rt][ct], 0, 0, 0);
        accf = __builtin_amdgcn_mfma_f32_16x16x32_bf16(afw, vfr, accf, 0, 0, 0);
    }

    // ---- fold store: wave w owns rows w*16..+15; C/D layout col=l16, row=quad*4+r ----
    {
        int frow = row0 + w * 16 + quad * 4;
        if (l16 < 2) {
#pragma unroll
            for (int r = 0; r < 4; r++)
                if (!TAIL || frow + r < M) el[(size_t)(frow + r) * 2 + l16] = accf[r];
        } else if (l16 < 4 && er) {
#pragma unroll
            for (int r = 0; r < 4; r++)
                if (!TAIL || frow + r < M) er[(size_t)(frow + r) * 2 + (l16 - 2)] = accf[r];
        }
    }
    __syncthreads();

    // ---- bounce C to LDS [64][264] bf16 ----
#pragma unroll
    for (int rt = 0; rt < 4; rt++)
#pragma unroll
        for (int ct = 0; ct < 4; ct++)
#pragma unroll
            for (int r = 0; r < 4; r++)
                lds[(rt * 16 + quad * 4 + r) * 264 + col0w + ct * 16 + l16] = f2bf(acc[rt][ct][r]);
    __syncthreads();

    // ---- coalesced store ----
#pragma unroll
    for (int i = 0; i < 8; i++) {
        int flat = i * 4096 + t * 16;
        int row = flat >> 9;
        int cb = flat & 511;
        int grow = row0 + row;
        if (!TAIL || grow < M)
            *(uint4*)((char*)C + (size_t)grow * 512 + cb) =
                *(const uint4*)((const char*)lds + row * 528 + cb);
    }
}

__global__ __launch_bounds__(256, 4) void gemm_fused(
    const float* __restrict__ A0, const float* __restrict__ A1, const float* __restrict__ A2,
    const unsigned short* __restrict__ W0, const unsigned short* __restrict__ W1,
    const unsigned short* __restrict__ W2,
    const unsigned short* __restrict__ V0, const unsigned short* __restrict__ V1,
    const unsigned short* __restrict__ V2,
    unsigned short* __restrict__ C0, unsigned short* __restrict__ C1,
    unsigned short* __restrict__ C2,
    float* __restrict__ el0, float* __restrict__ el1, float* __restrict__ el2,
    float* __restrict__ er0,
    int M0, int M1, int M2, int nb0, int nb01)
{
    __shared__ unsigned short lds[16896];   // union: A-stage 64x136 / C-bounce 64x264
    int b = blockIdx.x;
    const float* A; const unsigned short* Wp; const unsigned short* Vp;
    unsigned short* C; float* el; float* er; int M; int row0;
    if (b < nb0)       { A = A0; Wp = W0; Vp = V0; C = C0; el = el0; er = er0;     M = M0; row0 = b * 64; }
    else if (b < nb01) { A = A1; Wp = W1; Vp = V1; C = C1; el = el1; er = nullptr; M = M1; row0 = (b - nb0) * 64; }
    else               { A = A2; Wp = W2; Vp = V2; C = C2; el = el2; er = nullptr; M = M2; row0 = (b - nb01) * 64; }
    if (row0 + 64 <= M) gemm_body<false>(A, Wp, Vp, C, M, el, er, lds, row0);
    else                gemm_body<true >(A, Wp, Vp, C, M, el, er, lds, row0);
}

// ---------- CSR build ----------
__global__ void hist_kernel(const int* __restrict__ dst, int* __restrict__ deg, int Nb) {
    int t = blockIdx.x * blockDim.x + threadIdx.x;
    if (t < Nb) atomicAdd(&deg[dst[t]], 1);
}

// parallel 3-pass scan: per-4096-chunk local scan -> scan chunk totals -> add offsets
__global__ __launch_bounds__(1024) void scan_blocks(
    const int* __restrict__ deg, int* __restrict__ rowptr, int* __restrict__ wo,
    int* __restrict__ partials, int n)
{
    __shared__ int wsum[16];
    int t = threadIdx.x, lane = t & 63, w = t >> 6;
    int i0 = blockIdx.x * 4096 + t * 4;
    int4 v = make_int4(0, 0, 0, 0);
    if (i0 + 3 < n) v = *(const int4*)(deg + i0);
    else {
        if (i0 < n)     v.x = deg[i0];
        if (i0 + 1 < n) v.y = deg[i0 + 1];
        if (i0 + 2 < n) v.z = deg[i0 + 2];
        if (i0 + 3 < n) v.w = deg[i0 + 3];
    }
    int tsum = v.x + v.y + v.z + v.w;
    int x = tsum;
#pragma unroll
    for (int off = 1; off < 64; off <<= 1) {
        int y = __shfl_up(x, off);
        if (lane >= off) x += y;
    }
    if (lane == 63) wsum[w] = x;
    __syncthreads();
    if (w == 0) {
        int s = (lane < 16) ? wsum[lane] : 0;
#pragma unroll
        for (int off = 1; off < 16; off <<= 1) {
            int y = __shfl_up(s, off);
            if (lane >= off) s += y;
        }
        if (lane < 16) wsum[lane] = s;
    }
    __syncthreads();
    int wofs = (w > 0) ? wsum[w - 1] : 0;
    int e0 = wofs + (x - tsum);     // chunk-local exclusive prefix of element i0
    int e1 = e0 + v.x, e2 = e1 + v.y, e3 = e2 + v.z;
    if (i0 < n)     { wo[i0]     = e0; rowptr[i0 + 1] = e1; }
    if (i0 + 1 < n) { wo[i0 + 1] = e1; rowptr[i0 + 2] = e2; }
    if (i0 + 2 < n) { wo[i0 + 2] = e2; rowptr[i0 + 3] = e3; }
    if (i0 + 3 < n) { wo[i0 + 3] = e3; rowptr[i0 + 4] = e3 + v.w; }
    if (t == 0) partials[blockIdx.x] = wsum[15];
}

__global__ __launch_bounds__(1024) void scan_partials_k(int* __restrict__ partials, int nb) {
    __shared__ int wsum[16];
    int t = threadIdx.x, lane = t & 63, w = t >> 6;
    int v = (t < nb) ? partials[t] : 0;
    int x = v;
#pragma unroll
    for (int off = 1; off < 64; off <<= 1) {
        int y = __shfl_up(x, off);
        if (lane >= off) x += y;
    }
    if (lane == 63) wsum[w] = x;
    __syncthreads();
    if (w == 0) {
        int s = (lane < 16) ? wsum[lane] : 0;
#pragma unroll
        for (int off = 1; off < 16; off <<= 1) {
            int y = __shfl_up(s, off);
            if (lane >= off) s += y;
        }
        if (lane < 16) wsum[lane] = s;
    }
    __syncthreads();
    int wofs = (w > 0) ? wsum[w - 1] : 0;
    if (t < nb) partials[t] = wofs + (x - v);   // exclusive chunk offsets
}

__global__ void scan_add_k(int* __restrict__ rowptr, int* __restrict__ wo,
                           const int* __restrict__ partials, int n) {
    int i = blockIdx.x * 256 + threadIdx.x;
    if (i >= n) return;
    int ofs = partials[i >> 12];
    rowptr[i + 1] += ofs;
    wo[i] += ofs;
    if (i == 0) rowptr[0] = 0;
}

// ---------- fill CSR + precompute per-edge attention logits ----------
__global__ void fill_kernel(const int* __restrict__ src, const int* __restrict__ dst,
                            const float* __restrict__ er, const float* __restrict__ elh,
                            const float* __restrict__ ele,
                            int* __restrict__ wo, int* __restrict__ sidx,
                            int* __restrict__ eidx, float4* __restrict__ logits, int Nb) {
    int t = blockIdx.x * blockDim.x + threadIdx.x;
    if (t >= Nb) return;
    int d = dst[t], s = src[t];
    int p = atomicAdd(&wo[d], 1);
    float e0 = er[(size_t)d * 2], e1 = er[(size_t)d * 2 + 1];
    float h0 = elh[(size_t)s * 2], h1 = elh[(size_t)s * 2 + 1];
    float l0 = ele[(size_t)t * 2], l1 = ele[(size_t)t * 2 + 1];
    sidx[p] = s;
    eidx[p] = t;
    logits[p] = make_float4(lrelu(h0 + e0), lrelu(h1 + e1), lrelu(l0 + e0), lrelu(l1 + e1));
}

// ---------- aggregation: wave per atom, wave-parallel logits + pipelined row gather ----------
__global__ __launch_bounds__(256) void aggregate(
    const unsigned short* __restrict__ h, const unsigned short* __restrict__ e,
    const unsigned short* __restrict__ u,
    const float* __restrict__ er, const float* __restrict__ elu,
    const int* __restrict__ rowptr, const int* __restrict__ sidx,
    const int* __restrict__ eidx, const float4* __restrict__ logits,
    const int* __restrict__ gid,
    float* __restrict__ hm, int Na)
{
    int wid = (int)((blockIdx.x * (unsigned)blockDim.x + threadIdx.x) >> 6);
    int lane = threadIdx.x & 63;
    if (wid >= Na) return;
    const int a = wid;
    const float er0 = er[(size_t)a * 2], er1 = er[(size_t)a * 2 + 1];
    const int g = gid[a];
    const float eul0 = lrelu(elu[(size_t)g * 2] + er0);
    const float eul1 = lrelu(elu[(size_t)g * 2 + 1] + er1);
    const int rb = rowptr[a], re = rowptr[a + 1];

    // ---- pass A: wave-parallel max over all edge logits ----
    float m0 = eul0, m1 = eul1;
    for (int base = rb; base < re; base += 64) {
        int i = base + lane;
        float lm0 = -1e30f, lm1 = -1e30f;
        if (i < re) {
            float4 lg = logits[i];
            lm0 = fmaxf(lg.x, lg.z);
            lm1 = fmaxf(lg.y, lg.w);
        }
#pragma unroll
        for (int off = 32; off >= 1; off >>= 1) {
            lm0 = fmaxf(lm0, __shfl_xor(lm0, off));
            lm1 = fmaxf(lm1, __shfl_xor(lm1, off));
        }
        m0 = fmaxf(m0, lm0);
        m1 = fmaxf(m1, lm1);
    }

    float es0 = __expf(eul0 - m0), es1 = __expf(eul1 - m1);
    const int head = lane >> 5;
    const int d4 = lane << 2;
    float acc0, acc1, acc2, acc3;
    {
        float eu_sel = head ? es1 : es0;
        ushort4 uv = *(const ushort4*)(u + (size_t)g * 256 + d4);
        acc0 = eu_sel * bf2f(uv.x); acc1 = eu_sel * bf2f(uv.y);
        acc2 = eu_sel * bf2f(uv.z); acc3 = eu_sel * bf2f(uv.w);
    }

    // ---- pass B: exp weights (parallel), then pipelined weighted row gather ----
    for (int base = rb; base < re; base += 64) {
        int n = min(64, re - base);
        float xh0 = 0.f, xh1 = 0.f, xe0 = 0.f, xe1 = 0.f;
        int sv = 0, bv = 0;
        if (lane < n) {
            float4 lg = logits[base + lane];
            xh0 = __expf(lg.x - m0); xh1 = __expf(lg.y - m1);
            xe0 = __expf(lg.z - m0); xe1 = __expf(lg.w - m1);
            sv = sidx[base + lane];
            bv = eidx[base + lane];
        }
        float s0 = xh0 + xe0, s1 = xh1 + xe1;
#pragma unroll
        for (int off = 32; off >= 1; off >>= 1) {
            s0 += __shfl_xor(s0, off);
            s1 += __shfl_xor(s1, off);
        }
        es0 += s0; es1 += s1;

        for (int j = 0; j < n; j++) {
            int s_j = __shfl(sv, j), b_j = __shfl(bv, j);
            float wh0 = __shfl(xh0, j), wh1 = __shfl(xh1, j);
            float we0 = __shfl(xe0, j), we1 = __shfl(xe1, j);
            float wh = head ? wh1 : wh0;
            float we = head ? we1 : we0;
            ushort4 hv = *(const ushort4*)(h + (size_t)s_j * 256 + d4);
            ushort4 ev = *(const ushort4*)(e + (size_t)b_j * 256 + d4);
            acc0 += wh * bf2f(hv.x) + we * bf2f(ev.x);
            acc1 += wh * bf2f(hv.y) + we * bf2f(ev.y);
            acc2 += wh * bf2f(hv.z) + we * bf2f(ev.z);
            acc3 += wh * bf2f(hv.w) + we * bf2f(ev.w);
        }
    }

    float inv = 1.f / (head ? es1 : es0);
    acc0 *= inv; acc1 *= inv; acc2 *= inv; acc3 *= inv;
    // mean over heads: lanes<32 combine with lane+32
    float p0 = __shfl(acc0, (lane + 32) & 63);
    float p1 = __shfl(acc1, (lane + 32) & 63);
    float p2 = __shfl(acc2, (lane + 32) & 63);
    float p3 = __shfl(acc3, (lane + 32) & 63);
    if (lane < 32) {
        float4 o = make_float4(0.5f * (acc0 + p0), 0.5f * (acc1 + p1),
                               0.5f * (acc2 + p2), 0.5f * (acc3 + p3));
        *(float4*)(hm + (size_t)a * 128 + d4) = o;
    }
}

// ---------- BatchNorm stats ----------
__global__ void bnstats(const float* __restrict__ hm, float* __restrict__ sums, int Na) {
    int t = threadIdx.x;
    int c = t & 127, half = t >> 7;
    float s = 0.f, ss = 0.f;
    for (int r = blockIdx.x * 2 + half; r < Na; r += gridDim.x * 2) {
        float v = hm[(size_t)r * 128 + c];
        s += v; ss += v * v;
    }
    atomicAdd(&sums[c], s);
    atomicAdd(&sums[128 + c], ss);
}

// ---------- BN normalize + ReLU ----------
__global__ void bnapply(const float* __restrict__ hm, const float* __restrict__ sums,
                        const float* __restrict__ gamma, const float* __restrict__ beta,
                        float* __restrict__ out, int Na) {
    int t = threadIdx.x;
    int c = t & 127, half = t >> 7;
    float invn = 1.f / (float)Na;
    float mean = sums[c] * invn;
    float var = sums[128 + c] * invn - mean * mean;
    float scale = gamma[c] * rsqrtf(var + 1e-5f);
    float shift = beta[c] - mean * scale;
    for (int r = blockIdx.x * 2 + half; r < Na; r += gridDim.x * 2) {
        float v = hm[(size_t)r * 128 + c] * scale + shift;
        out[(size_t)r * 128 + c] = fmaxf(v, 0.f);
    }
}

// ---------- launch ----------
extern "C" void kernel_launch(void* const* d_in, const int* in_sizes, int n_in,
                              void* d_out, int out_size, void* d_ws, size_t ws_size,
                              hipStream_t stream)
{
    const float* atom   = (const float*)d_in[0];
    const float* bondf  = (const float*)d_in[1];
    const float* globf  = (const float*)d_in[2];
    const float* Wa     = (const float*)d_in[3];
    const float* Wb     = (const float*)d_in[4];
    const float* Wg     = (const float*)d_in[5];
    const float* attn_l = (const float*)d_in[6];
    const float* attn_r = (const float*)d_in[7];
    const float* gamma  = (const float*)d_in[8];
    const float* beta   = (const float*)d_in[9];
    const int* src      = (const int*)d_in[10];
    const int* dst      = (const int*)d_in[11];
    const int* gid      = (const int*)d_in[12];
    const int Na = in_sizes[0] / 128;
    const int Nb = in_sizes[1] / 128;
    const int Ng = in_sizes[2] / 128;

    char* w = (char*)d_ws;
    size_t off = 0;
    auto alloc = [&](size_t bytes) -> void* {
        void* p = w + off;
        off = (off + bytes + 255) & ~(size_t)255;
        return p;
    };
    unsigned short* h   = (unsigned short*)alloc((size_t)Na * 256 * 2);
    unsigned short* e   = (unsigned short*)alloc((size_t)Nb * 256 * 2);
    unsigned short* u   = (unsigned short*)alloc((size_t)Ng * 256 * 2);
    unsigned short* Wpa = (unsigned short*)alloc(32768 * 2);
    unsigned short* Wpb = (unsigned short*)alloc(32768 * 2);
    unsigned short* Wpg = (unsigned short*)alloc(32768 * 2);
    unsigned short* Vpa = (unsigned short*)alloc(4096 * 2);
    unsigned short* Vpb = (unsigned short*)alloc(4096 * 2);
    unsigned short* Vpg = (unsigned short*)alloc(4096 * 2);
    float* er   = (float*)alloc((size_t)Na * 2 * 4);
    float* elh  = (float*)alloc((size_t)Na * 2 * 4);
    float* ele  = (float*)alloc((size_t)Nb * 2 * 4);
    float* elu  = (float*)alloc((size_t)Ng * 2 * 4);
    int* deg    = (int*)alloc((size_t)Na * 4);
    int* rowptr = (int*)alloc((size_t)(Na + 1) * 4);
    int* wo     = (int*)alloc((size_t)Na * 4);
    int* partials = (int*)alloc(1024 * 4);
    int* sidx   = (int*)alloc((size_t)Nb * 4);
    int* eidx   = (int*)alloc((size_t)Nb * 4);
    float4* logits = (float4*)alloc((size_t)Nb * 16);
    float* hm   = (float*)alloc((size_t)Na * 128 * 4);
    float* sums = (float*)alloc(256 * 4);

    hipMemsetAsync(deg, 0, (size_t)Na * 4, stream);
    hipMemsetAsync(sums, 0, 256 * 4, stream);

    packW3<<<384, 256, 0, stream>>>(Wa, Wb, Wg, Wpa, Wpb, Wpg);
    makeVpack<<<3, 256, 0, stream>>>(Wa, Wb, Wg, attn_l, attn_r, Vpa, Vpb, Vpg);

    const int ba = (Na + 63) / 64, bb = (Nb + 63) / 64, bg = (Ng + 63) / 64;
    gemm_fused<<<ba + bb + bg, 256, 0, stream>>>(
        atom, bondf, globf, Wpa, Wpb, Wpg, Vpa, Vpb, Vpg,
        h, e, u, elh, ele, elu, er, Na, Nb, Ng, ba, ba + bb);

    hist_kernel<<<(Nb + 255) / 256, 256, 0, stream>>>(dst, deg, Nb);
    const int nchunks = (Na + 4095) / 4096;
    scan_blocks<<<nchunks, 1024, 0, stream>>>(deg, rowptr, wo, partials, Na);
    scan_partials_k<<<1, 1024, 0, stream>>>(partials, nchunks);
    scan_add_k<<<(Na + 255) / 256, 256, 0, stream>>>(rowptr, wo, partials, Na);
    fill_kernel<<<(Nb + 255) / 256, 256, 0, stream>>>(src, dst, er, elh, ele,
                                                      wo, sidx, eidx, logits, Nb);

    aggregate<<<(Na + 3) / 4, 256, 0, stream>>>(h, e, u, er, elu,
                                                rowptr, sidx, eidx, logits, gid, hm, Na);
    bnstats<<<256, 256, 0, stream>>>(hm, sums, Na);
    bnapply<<<512, 256, 0, stream>>>(hm, sums, gamma, beta, (float*)d_out, Na);
}